// Round 22
// baseline (85.111 us; speedup 1.0000x reference)
//
#include <hip/hip_runtime.h>

// out[n,k] = d[k] + sum_{ji,c} Bmat[k*49+ji][c] * bilinear_ji(proj[n,c,:,:])
// Bmat = WH·(w3·w2·w1); boxes constant -> pipeline fully linear in proj.
//
// k_mainf v5 = r21 + N-QUAD: block = (n-quad, quarter-row); 4 rows share each
// chunk's coeff registers (coeff traffic 257 -> 128 MB). Chunks shrink to
// 8 channels so LDS stays 50.4 KB ([4 rows][2 bufs][8][197]).
// Total delivered bytes 462 -> 333 MB at the ~6.8 TB/s aggregate ceiling.
//
// ws layout (floats):
//   WH    [490][512]   off 0
//   Y     [512][512]   off 250880
//   T1    [490][512]   off 513024
//   Bmat  [490][512]   off 763904
//   u2    [512]        off 1014784
//   vv    [512]        off 1015296
//   dpart [10][8]      off 1015808
//   part  [512*4][4][10] off 1015888

#define CHW4 25088   // float4 per proj row
#define STEP 1.8571428571428572f  // 13/7

// ---------- prep level 1: WH transpose (blocks 0..489) + u2=b2+w2*b1 (490..553)
__global__ __launch_bounds__(512) void k_prep1(
    const float* __restrict__ w_note, const float* __restrict__ w_reg,
    const float* __restrict__ w2, const float* __restrict__ b1,
    const float* __restrict__ b2,
    float* __restrict__ WH, float* __restrict__ u2) {
    int blk = blockIdx.x;
    int tid = threadIdx.x;
    if (blk < 490) {
        int k = blk / 49, ji = blk % 49;
        const float* wh = (k < 2) ? (w_note + k * 25088) : (w_reg + (k - 2) * 25088);
        WH[(size_t)blk * 512 + tid] = wh[tid * 49 + ji];
    } else {
        int wv = tid >> 6, lane = tid & 63;
        int o = (blk - 490) * 8 + wv;
        float s = 0.f;
        #pragma unroll
        for (int r = 0; r < 8; ++r) s += w2[(size_t)o * 512 + lane + r * 64] * b1[lane + r * 64];
        for (int off = 32; off; off >>= 1) s += __shfl_down(s, off);
        if (lane == 0) u2[o] = b2[o] + s;
    }
}

// ---------- prep level 2: {Y=w2*w1 | T1=WH*w3} (0..511) + vv=b3+w3*u2 (512..639)
__global__ __launch_bounds__(256) void k_prep2(
    const float* __restrict__ w1, const float* __restrict__ w2,
    const float* __restrict__ w3, const float* __restrict__ WH,
    const float* __restrict__ u2, const float* __restrict__ b3,
    float* __restrict__ Y, float* __restrict__ T1, float* __restrict__ vv) {
    int blk = blockIdx.x;
    int tid = threadIdx.x;
    if (blk < 512) {
        __shared__ float As[32][36];
        __shared__ float Bs[32][36];
        const float* A; const float* B; float* C; int M;
        if (blk < 256) { A = w2; B = w1; C = Y;  M = 512; }
        else           { A = WH; B = w3; C = T1; M = 490; }
        int t = blk & 255;
        int bx = t & 15, by = t >> 4;
        int lr = tid >> 3, lc = (tid & 7) << 2;
        int tx = tid & 15, ty = tid >> 4;
        float a00 = 0.f, a01 = 0.f, a10 = 0.f, a11 = 0.f;
        for (int kc = 0; kc < 512; kc += 32) {
            int gr = by * 32 + lr;
            float4 av = make_float4(0.f, 0.f, 0.f, 0.f);
            if (gr < M) av = *(const float4*)&A[(size_t)gr * 512 + kc + lc];
            *(float4*)&As[lr][lc] = av;
            *(float4*)&Bs[lr][lc] = *(const float4*)&B[(size_t)(kc + lr) * 512 + bx * 32 + lc];
            __syncthreads();
            #pragma unroll
            for (int kk = 0; kk < 32; ++kk) {
                float b0 = Bs[kk][tx * 2], b1v = Bs[kk][tx * 2 + 1];
                float x0 = As[ty * 2][kk], x1 = As[ty * 2 + 1][kk];
                a00 += x0 * b0; a01 += x0 * b1v;
                a10 += x1 * b0; a11 += x1 * b1v;
            }
            __syncthreads();
        }
        int r0 = by * 32 + ty * 2, c0 = bx * 32 + tx * 2;
        if (r0 < M)     { C[(size_t)r0 * 512 + c0] = a00; C[(size_t)r0 * 512 + c0 + 1] = a01; }
        if (r0 + 1 < M) { C[(size_t)(r0 + 1) * 512 + c0] = a10; C[(size_t)(r0 + 1) * 512 + c0 + 1] = a11; }
    } else {
        int wv = tid >> 6, lane = tid & 63;
        int o = (blk - 512) * 4 + wv;
        float s = 0.f;
        #pragma unroll
        for (int r = 0; r < 8; ++r) s += w3[(size_t)o * 512 + lane + r * 64] * u2[lane + r * 64];
        for (int off = 32; off; off >>= 1) s += __shfl_down(s, off);
        if (lane == 0) vv[o] = b3[o] + s;
    }
}

// ---------- prep level 3: Bmat=T1*Y (0..255) + dpart (256..335)
__global__ __launch_bounds__(256) void k_prep3(
    const float* __restrict__ T1, const float* __restrict__ Y,
    const float* __restrict__ w_note, const float* __restrict__ w_reg,
    const float* __restrict__ vv,
    float* __restrict__ Bmat, float* __restrict__ dpart) {
    int blk = blockIdx.x;
    int tid = threadIdx.x;
    if (blk < 256) {
        __shared__ float As[32][36];
        __shared__ float Bs[32][36];
        int bx = blk & 15, by = blk >> 4;
        int lr = tid >> 3, lc = (tid & 7) << 2;
        int tx = tid & 15, ty = tid >> 4;
        int gr = by * 32 + lr;
        float a00 = 0.f, a01 = 0.f, a10 = 0.f, a11 = 0.f;
        for (int kc = 0; kc < 512; kc += 32) {
            float4 av = make_float4(0.f, 0.f, 0.f, 0.f);
            if (gr < 490) av = *(const float4*)&T1[(size_t)gr * 512 + kc + lc];
            *(float4*)&As[lr][lc] = av;
            *(float4*)&Bs[lr][lc] = *(const float4*)&Y[(size_t)(kc + lr) * 512 + bx * 32 + lc];
            __syncthreads();
            #pragma unroll
            for (int kk = 0; kk < 32; ++kk) {
                float b0 = Bs[kk][tx * 2], b1v = Bs[kk][tx * 2 + 1];
                float x0 = As[ty * 2][kk], x1 = As[ty * 2 + 1][kk];
                a00 += x0 * b0; a01 += x0 * b1v;
                a10 += x1 * b0; a11 += x1 * b1v;
            }
            __syncthreads();
        }
        int r0 = by * 32 + ty * 2, c0 = bx * 32 + tx * 2;
        if (r0 < 490)     { Bmat[(size_t)r0 * 512 + c0] = a00; Bmat[(size_t)r0 * 512 + c0 + 1] = a01; }
        if (r0 + 1 < 490) { Bmat[(size_t)(r0 + 1) * 512 + c0] = a10; Bmat[(size_t)(r0 + 1) * 512 + c0 + 1] = a11; }
    } else {
        int t = blk - 256;             // 0..79
        int k = t >> 3, b8 = t & 7;
        const float* wh = (k < 2) ? (w_note + k * 25088) : (w_reg + (k - 2) * 25088);
        float s = 0.f;
        for (int i = b8 * 256 + tid; i < 25088; i += 2048) s += wh[i] * vv[i / 49];
        __shared__ float red[256];
        red[tid] = s;
        __syncthreads();
        for (int off = 128; off; off >>= 1) {
            if (tid < off) red[tid] += red[tid + off];
            __syncthreads();
        }
        if (tid == 0) dpart[k * 8 + b8] = red[0];
    }
}

// ---------- fused main v5: n-quad, 8-ch chunks, coeff-first vmcnt order
__global__ __launch_bounds__(256) void k_mainf(const float* __restrict__ proj,
                                               const float* __restrict__ Bmat,
                                               float* __restrict__ part) {
    __shared__ float X[4][2][8][197];   // 50,432 B; flat: row*3152 + buf*1576 + cc*197 + q*4
    int b = blockIdx.x;                 // 0..511
    int quad = b >> 2;                  // rows 4*quad .. 4*quad+3
    int qt = b & 3;                     // quarter-row: channels qt*128 + t*8 + cl
    int tid = threadIdx.x;
    int wv = tid >> 6, lane = tid & 63;
    int n0 = quad * 4;

    // staging coords: i = tid + s*256 (s<6), i = 1536+tid (s=6, tid<32)
    int ldsOff[7], srcOff[7];
    #pragma unroll
    for (int s = 0; s < 7; ++s) {
        int i = (s < 6) ? (tid + s * 256) : (1536 + tid);
        if (i > 1567) i = 1567;
        int row = i / 392, rem = i - row * 392;
        int cc = rem / 49, q = rem - cc * 49;
        ldsOff[s] = row * 3152 + cc * 197 + q * 4;
        srcOff[s] = row * CHW4 + rem;
    }
    const float4* srcQ = (const float4*)proj + (size_t)n0 * CHW4 + qt * 6272;

    // compute slot coords: set A = slot tid (all), set B = slot tid+256 (tid<136)
    const float base = STEP * 0.5f - 0.5f;
    int i00A, bidxA, i00B, bidxB;
    float wxA, wyA, wxB, wyB;
    {
        int o = tid;
        int ji = o >> 3, cl = o & 7;
        int j = (ji * 37) >> 8, i2 = ji - j * 7;
        float yv = base + j * STEP, xv = base + i2 * STEP;
        float y0f = floorf(yv), x0f = floorf(xv);
        wyA = yv - y0f; wxA = xv - x0f;
        i00A = cl * 197 + (int)y0f * 14 + (int)x0f;
        bidxA = ji * 512 + qt * 128 + cl;
    }
    {
        int o = tid + 256; if (o > 391) o = 391;
        int ji = o >> 3, cl = o & 7;
        int j = (ji * 37) >> 8, i2 = ji - j * 7;
        float yv = base + j * STEP, xv = base + i2 * STEP;
        float y0f = floorf(yv), x0f = floorf(xv);
        wyB = yv - y0f; wxB = xv - x0f;
        i00B = cl * 197 + (int)y0f * 14 + (int)x0f;
        bidxB = ji * 512 + qt * 128 + cl;
    }
    bool tB = tid < 136;
    bool t32 = tid < 32;

    float acc[4][10];
    #pragma unroll
    for (int r = 0; r < 4; ++r)
        #pragma unroll
        for (int k = 0; k < 10; ++k) acc[r][k] = 0.f;

    float* xflat = &X[0][0][0][0];
    float4 p0, p1, p2, p3, p4, p5, p6;

    // prologue: stage chunk 0 into buf 0
    p0 = srcQ[srcOff[0]]; p1 = srcQ[srcOff[1]]; p2 = srcQ[srcOff[2]];
    p3 = srcQ[srcOff[3]]; p4 = srcQ[srcOff[4]]; p5 = srcQ[srcOff[5]];
    if (t32) p6 = srcQ[srcOff[6]];
    *(float4*)&xflat[ldsOff[0]] = p0;
    *(float4*)&xflat[ldsOff[1]] = p1;
    *(float4*)&xflat[ldsOff[2]] = p2;
    *(float4*)&xflat[ldsOff[3]] = p3;
    *(float4*)&xflat[ldsOff[4]] = p4;
    *(float4*)&xflat[ldsOff[5]] = p5;
    if (t32) *(float4*)&xflat[ldsOff[6]] = p6;
    __syncthreads();

    int cur = 0;
    #pragma unroll 1
    for (int t = 0; t < 16; ++t) {
        // 1) coeff loads for chunk t — OLDEST in vmcnt FIFO (shared by 4 rows)
        float cA[10], cB[10];
        {
            const float* BpA = Bmat + bidxA + t * 8;
            #pragma unroll
            for (int k = 0; k < 10; ++k) cA[k] = BpA[(size_t)k * 25088];
            if (tB) {
                const float* BpB = Bmat + bidxB + t * 8;
                #pragma unroll
                for (int k = 0; k < 10; ++k) cB[k] = BpB[(size_t)k * 25088];
            }
        }
        __builtin_amdgcn_sched_barrier(0);
        // 2) proj loads for chunk t+1 — YOUNGER (survive coeff waits)
        if (t < 15) {
            const float4* sq = srcQ + (t + 1) * 392;
            p0 = sq[srcOff[0]]; p1 = sq[srcOff[1]]; p2 = sq[srcOff[2]];
            p3 = sq[srcOff[3]]; p4 = sq[srcOff[4]]; p5 = sq[srcOff[5]];
            if (t32) p6 = sq[srcOff[6]];
        }
        __builtin_amdgcn_sched_barrier(0);
        // 3) compute chunk t for 4 rows: LDS + coeff registers only
        const float* xc = xflat + cur * 1576;
        #pragma unroll
        for (int r = 0; r < 4; ++r) {
            const float* xr = xc + r * 3152 + i00A;
            float v00 = xr[0], v01 = xr[1], v10 = xr[14], v11 = xr[15];
            float top = v00 + (v01 - v00) * wxA;
            float bot = v10 + (v11 - v10) * wxA;
            float v = top + (bot - top) * wyA;
            #pragma unroll
            for (int k = 0; k < 10; ++k) acc[r][k] += v * cA[k];
        }
        if (tB) {
            #pragma unroll
            for (int r = 0; r < 4; ++r) {
                const float* xr = xc + r * 3152 + i00B;
                float v00 = xr[0], v01 = xr[1], v10 = xr[14], v11 = xr[15];
                float top = v00 + (v01 - v00) * wxB;
                float bot = v10 + (v11 - v10) * wxB;
                float v = top + (bot - top) * wyB;
                #pragma unroll
                for (int k = 0; k < 10; ++k) acc[r][k] += v * cB[k];
            }
        }
        // 4) scatter chunk t+1 into the other buffers
        if (t < 15) {
            float* xw = xflat + (cur ^ 1) * 1576;
            *(float4*)&xw[ldsOff[0]] = p0;
            *(float4*)&xw[ldsOff[1]] = p1;
            *(float4*)&xw[ldsOff[2]] = p2;
            *(float4*)&xw[ldsOff[3]] = p3;
            *(float4*)&xw[ldsOff[4]] = p4;
            *(float4*)&xw[ldsOff[5]] = p5;
            if (t32) *(float4*)&xw[ldsOff[6]] = p6;
        }
        __syncthreads();
        cur ^= 1;
    }

    // butterfly reduce; lane r*10+k stores (r,k)
    #pragma unroll
    for (int r = 0; r < 4; ++r)
        #pragma unroll
        for (int k = 0; k < 10; ++k) {
            float v = acc[r][k];
            v += __shfl_xor(v, 1);
            v += __shfl_xor(v, 2);
            v += __shfl_xor(v, 4);
            v += __shfl_xor(v, 8);
            v += __shfl_xor(v, 16);
            v += __shfl_xor(v, 32);
            if (lane == r * 10 + k)
                part[(((size_t)b * 4 + wv) * 4 + r) * 10 + k] = v;
        }
}

// out[n,k]: n = 4*quad+r; sum over 4 quarters x 4 waves
__global__ void k_reduce(const float* __restrict__ part,
                         const float* __restrict__ dpart,
                         const float* __restrict__ b_note, const float* __restrict__ b_reg,
                         float* __restrict__ out) {
    int idx = blockIdx.x * 256 + threadIdx.x;  // 0..5119
    int n = idx / 10, k = idx % 10;
    int quad = n >> 2, r = n & 3;
    float s = (k < 2) ? b_note[k] : b_reg[k - 2];
    for (int b8 = 0; b8 < 8; ++b8) s += dpart[k * 8 + b8];
    #pragma unroll
    for (int qt = 0; qt < 4; ++qt)
        for (int w = 0; w < 4; ++w)
            s += part[((((size_t)(quad * 4 + qt)) * 4 + w) * 4 + r) * 10 + k];
    if (k < 2) out[n * 2 + k] = s;
    else       out[1024 + n * 8 + (k - 2)] = s;
}

extern "C" void kernel_launch(void* const* d_in, const int* in_sizes, int n_in,
                              void* d_out, int out_size, void* d_ws, size_t ws_size,
                              hipStream_t stream) {
    const float* proj   = (const float*)d_in[0];
    const float* w1     = (const float*)d_in[1];
    const float* b1     = (const float*)d_in[2];
    const float* w2     = (const float*)d_in[3];
    const float* b2     = (const float*)d_in[4];
    const float* w3     = (const float*)d_in[5];
    const float* b3     = (const float*)d_in[6];
    const float* w_note = (const float*)d_in[7];
    const float* b_note = (const float*)d_in[8];
    const float* w_reg  = (const float*)d_in[9];
    const float* b_reg  = (const float*)d_in[10];

    float* ws    = (float*)d_ws;
    float* WH    = ws;
    float* Y     = WH + 250880;
    float* T1    = Y + 262144;
    float* Bmat  = T1 + 250880;
    float* u2    = Bmat + 250880;
    float* vv    = u2 + 512;
    float* dpart = vv + 512;
    float* part  = dpart + 80;
    float* out   = (float*)d_out;

    k_prep1<<<554, 512, 0, stream>>>(w_note, w_reg, w2, b1, b2, WH, u2);
    k_prep2<<<640, 256, 0, stream>>>(w1, w2, w3, WH, u2, b3, Y, T1, vv);
    k_prep3<<<336, 256, 0, stream>>>(T1, Y, w_note, w_reg, vv, Bmat, dpart);
    k_mainf<<<512, 256, 0, stream>>>(proj, Bmat, part);
    k_reduce<<<20, 256, 0, stream>>>(part, dpart, b_note, b_reg, out);
}